// Round 5
// baseline (164.348 us; speedup 1.0000x reference)
//
#include <hip/hip_runtime.h>

#define TEMP    0.5f
#define LOG2E   1.4426950408889634f
#define C2      (LOG2E / TEMP)        /* t = dot * C2 */
#define SQC2    1.6986436f            /* sqrt(C2): inputs pre-scaled so MFMA dot = t */
#define MSHIFT  160.0f                /* fixed base-2 softmax shift */
#define LN2     0.6931471805599453f
#define NROWS   16384
#define BHALF   8192
#define DDIM    128
#define PREPB   2048                  /* k_prep blocks = 524288/256 */

typedef __bf16 bf16x8 __attribute__((ext_vector_type(8)));
typedef float  f32x16 __attribute__((ext_vector_type(16)));
typedef float  f32x2  __attribute__((ext_vector_type(2)));

__device__ __forceinline__ float fexp2(float x) {
#if __has_builtin(__builtin_amdgcn_exp2f)
  return __builtin_amdgcn_exp2f(x);
#else
  return exp2f(x);
#endif
}

__device__ __forceinline__ unsigned short f2bf(float f) {
  unsigned int u = __float_as_uint(f);
  unsigned int r = (u + 0x7FFFu + ((u >> 16) & 1u)) >> 16;  // RNE
  return (unsigned short)r;
}

// ---------------------------------------------------------------------------
// zbF frag-major layout: for row r, k-index k:
//   g = r/32, lo = r%32, khi = k/8, j = k%8
//   short index = g*4096 + khi*256 + lo*8 + j
// A wave's frag load (fixed ks): 64 lanes read a contiguous 1KB block.
// Values are pre-scaled by SQC2, so an MFMA dot directly yields t = dot/T*log2e.
// ---------------------------------------------------------------------------

// k_prep: cast concat(z_i,z_j)*SQC2 fp32->bf16 into frag-major zbF; per-block
// partial dot(z_i,z_j) (UNscaled, exact fp32) -> Pp[block]; zero S.
__global__ void k_prep(const float* __restrict__ zi, const float* __restrict__ zj,
                       unsigned short* __restrict__ zbF,
                       float* __restrict__ S, float* __restrict__ Pp) {
  const int t   = blockIdx.x * 256 + threadIdx.x;   // 0..524287 float4 groups
  const int row = t >> 5;                           // 32 float4 per 128-elt row
  const int k0  = (t & 31) * 4;
  const float* src = (row < BHALF) ? (zi + (size_t)row * DDIM)
                                   : (zj + (size_t)(row - BHALF) * DDIM);
  float4 v = *reinterpret_cast<const float4*>(src + k0);

  const int g = row >> 5, lo = row & 31, khi = k0 >> 3, j0 = k0 & 7;
  ushort4 o;
  o.x = f2bf(v.x * SQC2); o.y = f2bf(v.y * SQC2);
  o.z = f2bf(v.z * SQC2); o.w = f2bf(v.w * SQC2);
  *reinterpret_cast<ushort4*>(zbF + (size_t)g * 4096 + khi * 256 + lo * 8 + j0) = o;

  float dot = 0.f;
  if (row < BHALF) {
    float4 w = *reinterpret_cast<const float4*>(zj + (size_t)row * DDIM + k0);
    dot = fmaf(v.x, w.x, fmaf(v.y, w.y, fmaf(v.z, w.z, v.w * w.w)));
  }
#pragma unroll
  for (int m = 32; m >= 1; m >>= 1) dot += __shfl_xor(dot, m, 64);
  __shared__ float red[4];
  if ((threadIdx.x & 63) == 0) red[threadIdx.x >> 6] = dot;
  __syncthreads();
  if (threadIdx.x == 0) Pp[blockIdx.x] = red[0] + red[1] + red[2] + red[3];

  if (t < NROWS) S[t] = 0.f;
}

// ---------------------------------------------------------------------------
// k_main: wave holds 128 persistent rows as MFMA *B* operand. Streams 32-col
// tiles as the A operand from frag-major zbF. No LDS, no barriers.
//
// Round-5 structure: WAR-free 3-accumulator rotation (acc0,acc1,acc2 then
// chain3 recycles acc0) + sched_group_barrier script {MFMA,16} then
// 16x{MFMA,1; VALU,3} so chains(2,3)'s 16 MFMAs interleave with the 48 VALU
// ops of exp(acc0/acc1). C-operand = -MSHIFT (inputs pre-scaled by sqrt(C2))
// so the exp section is exp2 + pk_add only.
// HISTORY: per-ks source interleaving (r1: 4 accs, r2: templated ping-pong)
// spilled catastrophically (WRITE_SIZE 1->162MB). Keep sections clean; let
// the scheduler do the interleave under SGB direction. Peak live accs = 3.
// ---------------------------------------------------------------------------

template <bool MASK>
__device__ __forceinline__ void expAcc(const f32x16& acc, f32x2& s, int d, int hi) {
#pragma unroll
  for (int k = 0; k < 8; ++k) {
    f32x2 e;
    e.x = fexp2(acc[2 * k]);
    e.y = fexp2(acc[2 * k + 1]);
    if (MASK) {
      const int r0 = 2 * k, r1 = 2 * k + 1;
      if (((r0 & 3) + 8 * (r0 >> 2) + 4 * hi) == d) e.x = 0.f;  // C/D reg map
      if (((r1 & 3) + 8 * (r1 >> 2) + 4 * hi) == d) e.y = 0.f;
    }
    s += e;                                                     // v_pk_add_f32
  }
}

#define MFMA_ __builtin_amdgcn_mfma_f32_32x32x16_bf16

template <bool MASK, bool RELOAD>
__device__ __forceinline__ void iterBody(bf16x8 (&a)[8], const bf16x8 (&b)[4][8],
                                         const f32x16& kC, f32x2 (&s)[4],
                                         const unsigned short* __restrict__ ap,
                                         int d0, int d1, int d2, int d3, int hi) {
  // chains 0,1
  f32x16 acc0 = MFMA_(a[0], b[0][0], kC, 0, 0, 0);
  f32x16 acc1 = MFMA_(a[0], b[1][0], kC, 0, 0, 0);
#pragma unroll
  for (int ks = 1; ks < 8; ++ks) {
    acc0 = MFMA_(a[ks], b[0][ks], acc0, 0, 0, 0);
    acc1 = MFMA_(a[ks], b[1][ks], acc1, 0, 0, 0);
  }
  // chain 2 -> acc2 (new reg set; no WAR vs exp of acc0/acc1)
  f32x16 acc2 = MFMA_(a[0], b[2][0], kC, 0, 0, 0);
#pragma unroll
  for (int ks = 1; ks < 8; ++ks) acc2 = MFMA_(a[ks], b[2][ks], acc2, 0, 0, 0);
  expAcc<MASK>(acc0, s[0], d0, hi);
  // chain 3 -> recycle acc0 (dead after its exp above); peak live accs = 3
  acc0 = MFMA_(a[0], b[3][0], kC, 0, 0, 0);
#pragma unroll
  for (int ks = 1; ks < 8; ++ks) acc0 = MFMA_(a[ks], b[3][ks], acc0, 0, 0, 0);
  expAcc<MASK>(acc1, s[1], d1, hi);
  // next-iteration A-frag reload; scheduler places the loads, vmcnt hides
  // under the remaining exp work.
  if constexpr (RELOAD) {
#pragma unroll
    for (int ks = 0; ks < 8; ++ks)
      a[ks] = *reinterpret_cast<const bf16x8*>(ap + (size_t)ks * 512);
  }
  expAcc<MASK>(acc2, s[2], d2, hi);
  expAcc<MASK>(acc0, s[3], d3, hi);

  // T19 schedule script for this block: 16 MFMA up front (chains 0,1), then
  // 16 x {1 MFMA, 3 VALU} = chains 2,3 interleaved with exp(acc0)+exp(acc1)
  // (2x24 VALU). Remaining instrs (reload, exp2/exp3 drain) free.
  __builtin_amdgcn_sched_group_barrier(0x8, 16, 0);
#pragma unroll
  for (int i = 0; i < 16; ++i) {
    __builtin_amdgcn_sched_group_barrier(0x8, 1, 0);
    __builtin_amdgcn_sched_group_barrier(0x2, 3, 0);
  }
}

__global__ __launch_bounds__(256, 2)
void k_main(const unsigned short* __restrict__ zbF, float* __restrict__ S) {
  const int wave = threadIdx.x >> 6;
  const int lane = threadIdx.x & 63;
  const int lo = lane & 31;
  const int hi = lane >> 5;
  const int rb = blockIdx.x & 31;       // 32 row blocks of 512 rows
  const int cc = blockIdx.x >> 5;       // 16 col chunks of 1024 cols
  const int row0w = rb * 512 + wave * 128;

  // persistent row frags (B operand): 4 row-tiles x 8 k-steps = 128 VGPRs
  bf16x8 b[4][8];
#pragma unroll
  for (int rt = 0; rt < 4; ++rt) {
    const unsigned short* bp = zbF + (size_t)((row0w >> 5) + rt) * 4096 + hi * 256 + lo * 8;
#pragma unroll
    for (int ks = 0; ks < 8; ++ks)
      b[rt][ks] = *reinterpret_cast<const bf16x8*>(bp + ks * 512);
  }

  f32x16 kC;                            // C-operand: -MSHIFT baked into acc
#pragma unroll
  for (int r = 0; r < 16; ++r) kC[r] = -MSHIFT;

  f32x2 s[4];
#pragma unroll
  for (int rt = 0; rt < 4; ++rt) { s[rt].x = 0.f; s[rt].y = 0.f; }

  const int c0base = cc * 1024;
  const unsigned short* abase = zbF + (size_t)(c0base >> 5) * 4096 + hi * 256 + lo * 8;

  bf16x8 a[8];
#pragma unroll
  for (int ks = 0; ks < 8; ++ks)
    a[ks] = *reinterpret_cast<const bf16x8*>(abase + ks * 512);

  for (int it = 0; it < 31; ++it) {
    const int c0 = c0base + it * 32;
    const int dr = c0 - row0w;
    const bool dg = (unsigned)dr < 128u;       // tile touches diagonal?
    const int rtd = dr >> 5;
    const unsigned short* apn = abase + (size_t)(it + 1) * 4096;
    if (!dg)
      iterBody<false, true>(a, b, kC, s, apn, -1, -1, -1, -1, hi);
    else
      iterBody<true, true>(a, b, kC, s, apn,
                           rtd == 0 ? lo : -1, rtd == 1 ? lo : -1,
                           rtd == 2 ? lo : -1, rtd == 3 ? lo : -1, hi);
  }
  { // peeled last iteration (no reload)
    const int dr = c0base + 31 * 32 - row0w;
    const bool dg = (unsigned)dr < 128u;
    const int rtd = dr >> 5;
    if (!dg)
      iterBody<false, false>(a, b, kC, s, abase, -1, -1, -1, -1, hi);
    else
      iterBody<true, false>(a, b, kC, s, abase,
                            rtd == 0 ? lo : -1, rtd == 1 ? lo : -1,
                            rtd == 2 ? lo : -1, rtd == 3 ? lo : -1, hi);
  }

  // row sums: lane-local scalar + fold hi halves, one atomic per row per chunk
#pragma unroll
  for (int rt = 0; rt < 4; ++rt) {
    float v = s[rt].x + s[rt].y;
    v += __shfl_xor(v, 32, 64);
    if (hi == 0) atomicAdd(&S[row0w + rt * 32 + lo], v);
  }
}

// ---------------------------------------------------------------------------
// k_fin: out = ( LN2 * sum_k (M + log2 S_k)  -  4 * sum Pp ) / N
// Linear -> single fused block reduction (1024 threads).
// ---------------------------------------------------------------------------
__global__ void k_fin(const float* __restrict__ S, const float* __restrict__ Pp,
                      float* __restrict__ out) {
  const int t = threadIdx.x;            // 1024 threads
  float q = 0.f;
  for (int r = t; r < NROWS; r += 1024)
    q += LN2 * (MSHIFT + __log2f(S[r]));
  for (int r = t; r < PREPB; r += 1024)
    q -= 4.0f * Pp[r];
  __shared__ float red[1024];
  red[t] = q;
  __syncthreads();
  for (int s2 = 512; s2 > 0; s2 >>= 1) {
    if (t < s2) red[t] += red[t + s2];
    __syncthreads();
  }
  if (t == 0) out[0] = red[0] / (float)NROWS;
}

// ---------------------------------------------------------------------------
extern "C" void kernel_launch(void* const* d_in, const int* in_sizes, int n_in,
                              void* d_out, int out_size, void* d_ws, size_t ws_size,
                              hipStream_t stream) {
  const float* zi = (const float*)d_in[0];
  const float* zj = (const float*)d_in[1];
  unsigned short* zbF = (unsigned short*)d_ws;                     // 4 MB
  float* S  = (float*)((char*)d_ws + (size_t)NROWS * DDIM * 2);    // 64 KB
  float* Pp = S + NROWS;                                           // 8 KB
  float* out = (float*)d_out;

  hipLaunchKernelGGL(k_prep, dim3(PREPB), dim3(256), 0, stream, zi, zj, zbF, S, Pp);
  hipLaunchKernelGGL(k_main, dim3(512),  dim3(256), 0, stream, zbF, S);
  hipLaunchKernelGGL(k_fin,  dim3(1),    dim3(1024), 0, stream, S, Pp, out);
}

// Round 6
// 148.344 us; speedup vs baseline: 1.1079x; 1.1079x over previous
//
#include <hip/hip_runtime.h>

#define TEMP    0.5f
#define LOG2E   1.4426950408889634f
#define C2      (LOG2E / TEMP)        /* t = dot * C2 */
#define SQC2    1.6986436f            /* sqrt(C2): inputs pre-scaled so MFMA dot = t */
#define MSHIFT  160.0f                /* fixed base-2 softmax shift */
#define LN2     0.6931471805599453f
#define NROWS   16384
#define BHALF   8192
#define DDIM    128
#define PREPB   2048                  /* k_prep blocks = 524288/256 */

typedef __bf16 bf16x8 __attribute__((ext_vector_type(8)));
typedef float  f32x16 __attribute__((ext_vector_type(16)));
typedef float  f32x2  __attribute__((ext_vector_type(2)));

__device__ __forceinline__ float fexp2(float x) {
#if __has_builtin(__builtin_amdgcn_exp2f)
  return __builtin_amdgcn_exp2f(x);
#else
  return exp2f(x);
#endif
}

__device__ __forceinline__ unsigned short f2bf(float f) {
  unsigned int u = __float_as_uint(f);
  unsigned int r = (u + 0x7FFFu + ((u >> 16) & 1u)) >> 16;  // RNE
  return (unsigned short)r;
}

// ---------------------------------------------------------------------------
// zbF frag-major layout: for row r, k-index k:
//   g = r/32, lo = r%32, khi = k/8, j = k%8
//   short index = g*4096 + khi*256 + lo*8 + j
// A wave's frag load (fixed ks): 64 lanes read a contiguous 1KB block.
// Values are pre-scaled by SQC2, so an MFMA dot directly yields t = dot/T*log2e.
// ---------------------------------------------------------------------------

// k_prep: cast concat(z_i,z_j)*SQC2 fp32->bf16 into frag-major zbF; per-block
// partial dot(z_i,z_j) (UNscaled, exact fp32) -> Pp[block]; zero S.
__global__ void k_prep(const float* __restrict__ zi, const float* __restrict__ zj,
                       unsigned short* __restrict__ zbF,
                       float* __restrict__ S, float* __restrict__ Pp) {
  const int t   = blockIdx.x * 256 + threadIdx.x;   // 0..524287 float4 groups
  const int row = t >> 5;                           // 32 float4 per 128-elt row
  const int k0  = (t & 31) * 4;
  const float* src = (row < BHALF) ? (zi + (size_t)row * DDIM)
                                   : (zj + (size_t)(row - BHALF) * DDIM);
  float4 v = *reinterpret_cast<const float4*>(src + k0);

  const int g = row >> 5, lo = row & 31, khi = k0 >> 3, j0 = k0 & 7;
  ushort4 o;
  o.x = f2bf(v.x * SQC2); o.y = f2bf(v.y * SQC2);
  o.z = f2bf(v.z * SQC2); o.w = f2bf(v.w * SQC2);
  *reinterpret_cast<ushort4*>(zbF + (size_t)g * 4096 + khi * 256 + lo * 8 + j0) = o;

  float dot = 0.f;
  if (row < BHALF) {
    float4 w = *reinterpret_cast<const float4*>(zj + (size_t)row * DDIM + k0);
    dot = fmaf(v.x, w.x, fmaf(v.y, w.y, fmaf(v.z, w.z, v.w * w.w)));
  }
#pragma unroll
  for (int m = 32; m >= 1; m >>= 1) dot += __shfl_xor(dot, m, 64);
  __shared__ float red[4];
  if ((threadIdx.x & 63) == 0) red[threadIdx.x >> 6] = dot;
  __syncthreads();
  if (threadIdx.x == 0) Pp[blockIdx.x] = red[0] + red[1] + red[2] + red[3];

  if (t < NROWS) S[t] = 0.f;
}

// ---------------------------------------------------------------------------
// k_main (round 6): THIN WAVES. Each wave owns 32 persistent rows (b[8] = 32
// VGPRs) and streams 2048 cols (64 iters x 32 cols), one 8-MFMA chain + one
// exp section per iter. Per-wave footprint ~114 regs -> 4 waves/SIMD
// (__launch_bounds__(256,4)). MFMA/VALU overlap comes from TLP across the 4
// phase-independent waves, not from intra-wave scheduling.
// HISTORY: fat-wave variants (b[4][8]=128 regs, 2 waves/SIMD) had zero
// register headroom: every extra live acc spilled catastrophically
// (r1/r2/r5: WRITE_SIZE 1MB -> 19-162MB). Section order within a wave stays
// serial (chain -> reload -> exp); do NOT source-interleave.
// C-operand = -MSHIFT baked in (inputs pre-scaled by sqrt(C2), r5-validated)
// so exp section is exp2 + pk_add only.
// ---------------------------------------------------------------------------

template <bool MASK>
__device__ __forceinline__ void expAcc(const f32x16& acc, f32x2& s, int d, int hi) {
#pragma unroll
  for (int k = 0; k < 8; ++k) {
    f32x2 e;
    e.x = fexp2(acc[2 * k]);
    e.y = fexp2(acc[2 * k + 1]);
    if (MASK) {
      const int r0 = 2 * k, r1 = 2 * k + 1;
      if (((r0 & 3) + 8 * (r0 >> 2) + 4 * hi) == d) e.x = 0.f;  // C/D reg map
      if (((r1 & 3) + 8 * (r1 >> 2) + 4 * hi) == d) e.y = 0.f;
    }
    s += e;                                                     // v_pk_add_f32
  }
}

#define MFMA_ __builtin_amdgcn_mfma_f32_32x32x16_bf16

__global__ __launch_bounds__(256, 4)
void k_main(const unsigned short* __restrict__ zbF, float* __restrict__ S) {
  const int wave = threadIdx.x >> 6;
  const int lane = threadIdx.x & 63;
  const int lo = lane & 31;
  const int hi = lane >> 5;
  const int rb = blockIdx.x & 127;      // 128 row blocks of 128 rows
  const int cc = blockIdx.x >> 7;       // 8 col chunks of 2048 cols
  const int row0w = rb * 128 + wave * 32;

  // persistent row frags (B operand): 1 row-tile x 8 k-steps = 32 VGPRs
  bf16x8 b[8];
  {
    const unsigned short* bp = zbF + (size_t)(row0w >> 5) * 4096 + hi * 256 + lo * 8;
#pragma unroll
    for (int ks = 0; ks < 8; ++ks)
      b[ks] = *reinterpret_cast<const bf16x8*>(bp + ks * 512);
  }

  f32x16 kC;                            // C-operand: -MSHIFT baked into acc
#pragma unroll
  for (int r = 0; r < 16; ++r) kC[r] = -MSHIFT;

  f32x2 s = {0.f, 0.f};

  const int c0base = cc * 2048;
  const unsigned short* abase = zbF + (size_t)(c0base >> 5) * 4096 + hi * 256 + lo * 8;

  bf16x8 a[8];
#pragma unroll
  for (int ks = 0; ks < 8; ++ks)
    a[ks] = *reinterpret_cast<const bf16x8*>(abase + ks * 512);

  for (int it = 0; it < 64; ++it) {
    // both tiles 32-aligned -> diagonal tile iff dr == 0
    const int dr = c0base + it * 32 - row0w;

    f32x16 acc = MFMA_(a[0], b[0], kC, 0, 0, 0);
#pragma unroll
    for (int ks = 1; ks < 8; ++ks)
      acc = MFMA_(a[ks], b[ks], acc, 0, 0, 0);

    // pipelined single-buffer reload: a[] dead after the chain; vmcnt wait
    // lands after the exp section.
    if (it + 1 < 64) {
      const unsigned short* ap = abase + (size_t)(it + 1) * 4096;
#pragma unroll
      for (int ks = 0; ks < 8; ++ks)
        a[ks] = *reinterpret_cast<const bf16x8*>(ap + ks * 512);
    }

    if (dr != 0) expAcc<false>(acc, s, -1, hi);
    else         expAcc<true >(acc, s, lo, hi);
  }

  // row sums: fold hi half, one atomic per row per chunk
  float v = s.x + s.y;
  v += __shfl_xor(v, 32, 64);
  if (hi == 0) atomicAdd(&S[row0w + lo], v);
}

// ---------------------------------------------------------------------------
// k_fin: out = ( LN2 * sum_k (M + log2 S_k)  -  4 * sum Pp ) / N
// Linear -> single fused block reduction (1024 threads).
// ---------------------------------------------------------------------------
__global__ void k_fin(const float* __restrict__ S, const float* __restrict__ Pp,
                      float* __restrict__ out) {
  const int t = threadIdx.x;            // 1024 threads
  float q = 0.f;
  for (int r = t; r < NROWS; r += 1024)
    q += LN2 * (MSHIFT + __log2f(S[r]));
  for (int r = t; r < PREPB; r += 1024)
    q -= 4.0f * Pp[r];
  __shared__ float red[1024];
  red[t] = q;
  __syncthreads();
  for (int s2 = 512; s2 > 0; s2 >>= 1) {
    if (t < s2) red[t] += red[t + s2];
    __syncthreads();
  }
  if (t == 0) out[0] = red[0] / (float)NROWS;
}

// ---------------------------------------------------------------------------
extern "C" void kernel_launch(void* const* d_in, const int* in_sizes, int n_in,
                              void* d_out, int out_size, void* d_ws, size_t ws_size,
                              hipStream_t stream) {
  const float* zi = (const float*)d_in[0];
  const float* zj = (const float*)d_in[1];
  unsigned short* zbF = (unsigned short*)d_ws;                     // 4 MB
  float* S  = (float*)((char*)d_ws + (size_t)NROWS * DDIM * 2);    // 64 KB
  float* Pp = S + NROWS;                                           // 8 KB
  float* out = (float*)d_out;

  hipLaunchKernelGGL(k_prep, dim3(PREPB), dim3(256), 0, stream, zi, zj, zbF, S, Pp);
  hipLaunchKernelGGL(k_main, dim3(1024), dim3(256), 0, stream, zbF, S);
  hipLaunchKernelGGL(k_fin,  dim3(1),    dim3(1024), 0, stream, S, Pp, out);
}